// Round 11
// baseline (738.105 us; speedup 1.0000x reference)
//
#include <hip/hip_runtime.h>

#define N_NODES 100000
#define M_EDGES 1600000
#define CH 64
#define NPB 64                               // nodes per bucket (col >> 6)
#define NB ((N_NODES + NPB - 1) / NPB)       // 1563 buckets
#define CAP 1536                             // padded slots per bucket (mean 1024 + 16 sigma)
#define PART_CHUNK 16384
#define PART_BLOCKS ((M_EDGES + PART_CHUNK - 1) / PART_CHUNK)  // 98
#define GROWS 192                            // gemm rows per block
#define GBLKS ((N_NODES + GROWS - 1) / GROWS)  // 521

// f32 -> bf16 (RNE) pack of two channels into one uint
__device__ __forceinline__ unsigned int pack_bf16x2(float a, float b) {
    unsigned int ua = __float_as_uint(a);
    ua = (ua + 0x7fffu + ((ua >> 16) & 1u)) >> 16;
    unsigned int ub = __float_as_uint(b);
    ub = (ub + 0x7fffu + ((ub >> 16) & 1u)) >> 16;
    return ua | (ub << 16);
}
__device__ __forceinline__ float bf_lo(unsigned int u) { return __uint_as_float(u << 16); }
__device__ __forceinline__ float bf_hi(unsigned int u) { return __uint_as_float(u & 0xffff0000u); }

// ---------- partition into PADDED 64-node bucket regions: hist -> claim -> scatter ----------
// bucket b owns pairs[b*CAP .. b*CAP+count_b); blocks claim sub-ranges via bcur (memset 0).
__global__ __launch_bounds__(256) void k_partition(const int* __restrict__ row, const int* __restrict__ col,
                                                   int* __restrict__ bcur, unsigned int* __restrict__ pairs) {
    __shared__ int h[NB];
    int tid = threadIdx.x;
    int c = blockIdx.x;
    for (int i = tid; i < NB; i += 256) h[i] = 0;
    __syncthreads();
    const int4* c4 = (const int4*)col;
    const int4* r4 = (const int4*)row;
    int start4 = c * (PART_CHUNK / 4);
    int end4 = min(M_EDGES / 4, start4 + PART_CHUNK / 4);
    // pass 1: LDS histogram of this chunk
    for (int e = start4 + tid; e < end4; e += 256) {
        int4 v = c4[e];
        atomicAdd(&h[v.x >> 6], 1);
        atomicAdd(&h[v.y >> 6], 1);
        atomicAdd(&h[v.z >> 6], 1);
        atomicAdd(&h[v.w >> 6], 1);
    }
    __syncthreads();
    // claim contiguous sub-ranges within each bucket's padded region
    for (int i = tid; i < NB; i += 256) {
        int cnt = h[i];
        h[i] = cnt ? (i * CAP + atomicAdd(&bcur[i], cnt)) : 0;
    }
    __syncthreads();
    // pass 2: scatter packed (row<<6 | col&63); chunk data L2-resident from pass 1
    for (int e = start4 + tid; e < end4; e += 256) {
        int4 cc = c4[e];
        int4 rr = r4[e];
        int pos;
        pos = atomicAdd(&h[cc.x >> 6], 1);
        pairs[pos] = ((unsigned int)rr.x << 6) | (unsigned int)(cc.x & 63);
        pos = atomicAdd(&h[cc.y >> 6], 1);
        pairs[pos] = ((unsigned int)rr.y << 6) | (unsigned int)(cc.y & 63);
        pos = atomicAdd(&h[cc.z >> 6], 1);
        pairs[pos] = ((unsigned int)rr.z << 6) | (unsigned int)(cc.z & 63);
        pos = atomicAdd(&h[cc.w >> 6], 1);
        pairs[pos] = ((unsigned int)rr.w << 6) | (unsigned int)(cc.w & 63);
    }
}

// ---------- per-bucket degree count -> dis (needed by gemm's scaling) ----------
__global__ __launch_bounds__(256) void k_deg(const int* __restrict__ bcur, const unsigned int* __restrict__ pairs,
                                             float* __restrict__ dis) {
    __shared__ int lcnt[NPB];
    int b = blockIdx.x, t = threadIdx.x;
    if (t < NPB) lcnt[t] = 0;
    __syncthreads();
    int cnt = bcur[b];
    int s0 = b * CAP;
    for (int e = t; e < cnt; e += 256)
        atomicAdd(&lcnt[pairs[s0 + e] & 63u], 1);
    __syncthreads();
    if (t < NPB) {
        int node = b * NPB + t;
        if (node < N_NODES) dis[node] = 1.0f / sqrtf((float)(lcnt[t] + 1));  // degree incl. self-loop
    }
}

// ---------- g = dis[r] * (x @ W), packed bf16; wave = 16-col quad, lane = row, 3 rows/thread ----------
__global__ __launch_bounds__(256) void k_gemm_g(const float* __restrict__ x, const float* __restrict__ W,
                                                const float* __restrict__ dis, unsigned int* __restrict__ g2) {
    __shared__ float sW[64][64];
    __shared__ float sXf[GROWS * 65];  // [row][k] with +1 pad
    int t = threadIdx.x;
    int row0 = blockIdx.x * GROWS;
    int nrows = min(GROWS, N_NODES - row0);

    for (int i = t; i < 64 * 64; i += 256) sW[i >> 6][i & 63] = W[i];
    const float4* xv = (const float4*)x;
    for (int idx = t; idx < GROWS * 16; idx += 256) {
        int r = idx >> 4, c4 = idx & 15;
        float4 v = (r < nrows) ? xv[(size_t)(row0 + r) * 16 + c4] : make_float4(0.f, 0.f, 0.f, 0.f);
        sXf[r * 65 + c4 * 4 + 0] = v.x;
        sXf[r * 65 + c4 * 4 + 1] = v.y;
        sXf[r * 65 + c4 * 4 + 2] = v.z;
        sXf[r * 65 + c4 * 4 + 3] = v.w;
    }
    __syncthreads();

    int q = t >> 6;          // wave id -> col quad
    int rid = t & 63;        // lane -> row
    int c0 = q * 16;
    float acc0[16], acc1[16], acc2[16];
#pragma unroll
    for (int j = 0; j < 16; j++) { acc0[j] = 0.f; acc1[j] = 0.f; acc2[j] = 0.f; }

    for (int k = 0; k < 64; k++) {
        float xv0 = sXf[rid * 65 + k];
        float xv1 = sXf[(rid + 64) * 65 + k];
        float xv2 = sXf[(rid + 128) * 65 + k];
        const float4* wp = (const float4*)&sW[k][c0];  // same addr across wave: broadcast
        float4 w0 = wp[0], w1 = wp[1], w2 = wp[2], w3 = wp[3];
        float wv[16] = {w0.x, w0.y, w0.z, w0.w, w1.x, w1.y, w1.z, w1.w,
                        w2.x, w2.y, w2.z, w2.w, w3.x, w3.y, w3.z, w3.w};
#pragma unroll
        for (int j = 0; j < 16; j++) {
            acc0[j] += xv0 * wv[j];
            acc1[j] += xv1 * wv[j];
            acc2[j] += xv2 * wv[j];
        }
    }

#pragma unroll
    for (int jr = 0; jr < 3; jr++) {
        int r = rid + jr * 64;
        int gr = row0 + r;
        if (r < nrows) {
            float* accp = (jr == 0) ? acc0 : (jr == 1) ? acc1 : acc2;  // unrolled: compile-time
            float d = dis[gr];
            uint4 wlo, whi;
            wlo.x = pack_bf16x2(d * accp[0], d * accp[1]);
            wlo.y = pack_bf16x2(d * accp[2], d * accp[3]);
            wlo.z = pack_bf16x2(d * accp[4], d * accp[5]);
            wlo.w = pack_bf16x2(d * accp[6], d * accp[7]);
            whi.x = pack_bf16x2(d * accp[8], d * accp[9]);
            whi.y = pack_bf16x2(d * accp[10], d * accp[11]);
            whi.z = pack_bf16x2(d * accp[12], d * accp[13]);
            whi.w = pack_bf16x2(d * accp[14], d * accp[15]);
            unsigned int base = (unsigned int)gr * 32 + q * 8;
            *reinterpret_cast<uint4*>(&g2[base]) = wlo;
            *reinterpret_cast<uint4*>(&g2[base + 4]) = whi;
        }
    }
}

// ---------- aggregation: LDS accumulator per 64-node bucket; no sorted edges needed ----------
// block b: acc[64][65] f32; per edge gather g2[row] (8 lanes x uint4) -> LDS atomic add at col.
// epilogue: out = dis*(acc + g2[node]) + bias, fully coalesced.
__global__ __launch_bounds__(256) void k_agg_lds(const int* __restrict__ bcur, const unsigned int* __restrict__ pairs,
                                                 const float* __restrict__ dis, const unsigned int* __restrict__ g2,
                                                 const float* __restrict__ bias, float* __restrict__ out) {
    __shared__ float acc[NPB * 65];  // +1 pad: bank = (c + 8*sub + k) % 32 -> node-spread
    int b = blockIdx.x, t = threadIdx.x;
    for (int i = t; i < NPB * 65; i += 256) acc[i] = 0.0f;
    __syncthreads();

    int cnt = bcur[b];
    int s0 = b * CAP;
    int wid = t >> 6, lane = t & 63;
    int eslot = lane >> 3;   // 8 edges per wave
    int sub = lane & 7;      // channel octet
    const uint4* gq = (const uint4*)g2;

    for (int i = wid * 8 + eslot; i < cnt; i += 128) {  // 4 slots deep, MLP=4
        int i1 = i + 32, i2 = i + 64, i3 = i + 96;
        unsigned int p0 = pairs[s0 + i];
        unsigned int p1 = (i1 < cnt) ? pairs[s0 + i1] : p0;
        unsigned int p2 = (i2 < cnt) ? pairs[s0 + i2] : p0;
        unsigned int p3 = (i3 < cnt) ? pairs[s0 + i3] : p0;
        uint4 u0 = gq[(p0 >> 6) * 8 + sub];
        uint4 u1 = gq[(p1 >> 6) * 8 + sub];
        uint4 u2 = gq[(p2 >> 6) * 8 + sub];
        uint4 u3 = gq[(p3 >> 6) * 8 + sub];
        int a0 = (int)(p0 & 63u) * 65 + sub * 8;
        atomicAdd(&acc[a0 + 0], bf_lo(u0.x)); atomicAdd(&acc[a0 + 1], bf_hi(u0.x));
        atomicAdd(&acc[a0 + 2], bf_lo(u0.y)); atomicAdd(&acc[a0 + 3], bf_hi(u0.y));
        atomicAdd(&acc[a0 + 4], bf_lo(u0.z)); atomicAdd(&acc[a0 + 5], bf_hi(u0.z));
        atomicAdd(&acc[a0 + 6], bf_lo(u0.w)); atomicAdd(&acc[a0 + 7], bf_hi(u0.w));
        if (i1 < cnt) {
            int a = (int)(p1 & 63u) * 65 + sub * 8;
            atomicAdd(&acc[a + 0], bf_lo(u1.x)); atomicAdd(&acc[a + 1], bf_hi(u1.x));
            atomicAdd(&acc[a + 2], bf_lo(u1.y)); atomicAdd(&acc[a + 3], bf_hi(u1.y));
            atomicAdd(&acc[a + 4], bf_lo(u1.z)); atomicAdd(&acc[a + 5], bf_hi(u1.z));
            atomicAdd(&acc[a + 6], bf_lo(u1.w)); atomicAdd(&acc[a + 7], bf_hi(u1.w));
        }
        if (i2 < cnt) {
            int a = (int)(p2 & 63u) * 65 + sub * 8;
            atomicAdd(&acc[a + 0], bf_lo(u2.x)); atomicAdd(&acc[a + 1], bf_hi(u2.x));
            atomicAdd(&acc[a + 2], bf_lo(u2.y)); atomicAdd(&acc[a + 3], bf_hi(u2.y));
            atomicAdd(&acc[a + 4], bf_lo(u2.z)); atomicAdd(&acc[a + 5], bf_hi(u2.z));
            atomicAdd(&acc[a + 6], bf_lo(u2.w)); atomicAdd(&acc[a + 7], bf_hi(u2.w));
        }
        if (i3 < cnt) {
            int a = (int)(p3 & 63u) * 65 + sub * 8;
            atomicAdd(&acc[a + 0], bf_lo(u3.x)); atomicAdd(&acc[a + 1], bf_hi(u3.x));
            atomicAdd(&acc[a + 2], bf_lo(u3.y)); atomicAdd(&acc[a + 3], bf_hi(u3.y));
            atomicAdd(&acc[a + 4], bf_lo(u3.z)); atomicAdd(&acc[a + 5], bf_hi(u3.z));
            atomicAdd(&acc[a + 6], bf_lo(u3.w)); atomicAdd(&acc[a + 7], bf_hi(u3.w));
        }
    }
    __syncthreads();

    // epilogue: 2 channels per thread (one packed self-loop uint), coalesced float2 stores
    for (int idx = t; idx < NPB * 32; idx += 256) {
        int loc = idx >> 5, chp = idx & 31;         // node-local, channel-pair
        int node = b * NPB + loc;
        if (node < N_NODES) {
            unsigned int su = g2[(unsigned int)node * 32 + chp];  // self-loop term
            float d = dis[node];
            float2 bv = *reinterpret_cast<const float2*>(&bias[chp * 2]);
            float v0 = d * (acc[loc * 65 + chp * 2 + 0] + bf_lo(su)) + bv.x;
            float v1 = d * (acc[loc * 65 + chp * 2 + 1] + bf_hi(su)) + bv.y;
            *reinterpret_cast<float2*>(&out[(size_t)node * CH + chp * 2]) = make_float2(v0, v1);
        }
    }
}

extern "C" void kernel_launch(void* const* d_in, const int* in_sizes, int n_in,
                              void* d_out, int out_size, void* d_ws, size_t ws_size,
                              hipStream_t stream) {
    const float* x  = (const float*)d_in[0];
    const int*   ei = (const int*)d_in[1];  // [2, M] flat int32
    const float* W  = (const float*)d_in[2];
    const float* bv = (const float*)d_in[3];
    float* out = (float*)d_out;

    const int* row = ei;
    const int* col = ei + M_EDGES;

    // workspace layout (~25.6 MB):
    char* ws = (char*)d_ws;
    int*          bcur  = (int*)(ws + 0);                    // NB*4 = 6,252 B (memset 0)
    float*        dis   = (float*)(ws + (512 << 10));        // 400,000 B
    unsigned int* g2    = (unsigned int*)(ws + (3u << 20));  // 12,800,000 B bf16 g (3 .. 15.8 MB)
    unsigned int* pairs = (unsigned int*)(ws + (16u << 20)); // NB*CAP*4 = 9,603,072 B (16 .. 25.6 MB)

    hipMemsetAsync(bcur, 0, NB * sizeof(int), stream);

    k_partition<<<PART_BLOCKS, 256, 0, stream>>>(row, col, bcur, pairs);
    k_deg<<<NB, 256, 0, stream>>>(bcur, pairs, dis);
    k_gemm_g<<<GBLKS, 256, 0, stream>>>(x, W, dis, g2);
    k_agg_lds<<<NB, 256, 0, stream>>>(bcur, pairs, dis, g2, bv, out);
}